// Round 1
// baseline (243.747 us; speedup 1.0000x reference)
//
#include <hip/hip_runtime.h>

#define Bdim 32
#define Tdim 256
#define Cdim 1024

typedef unsigned short u16;
typedef unsigned int u32;
typedef __bf16 bf16x8 __attribute__((ext_vector_type(8)));
typedef float f32x4 __attribute__((ext_vector_type(4)));

__device__ __forceinline__ float bf2f(u32 u) {
    union { u32 i; float f; } v; v.i = u << 16; return v.f;
}
__device__ __forceinline__ u16 f2bf(float f) {
    union { float f; u32 i; } v; v.f = f;
    u32 u = v.i;
    return (u16)((u + 0x7fffu + ((u >> 16) & 1u)) >> 16);  // RNE
}

__device__ __forceinline__ void gload16(const u16* g, u16* l) {
    __builtin_amdgcn_global_load_lds(
        (__attribute__((address_space(1))) const void*)g,
        (__attribute__((address_space(3))) void*)l, 16, 0, 0);
}

// ---- fused prep (x mixing -> bf16) + weight convert ---------------------------
__global__ __launch_bounds__(256) void prep_fused(
    const float* __restrict__ x, const float* __restrict__ tmk,
    const float* __restrict__ tmv, const float* __restrict__ tmr,
    u16* __restrict__ xk, u16* __restrict__ xv, u16* __restrict__ xr,
    const float* __restrict__ w0, const float* __restrict__ w1,
    const float* __restrict__ w2, const float* __restrict__ w3,
    u16* __restrict__ o0, u16* __restrict__ o1,
    u16* __restrict__ o2, u16* __restrict__ o3)
{
    int bid = blockIdx.x;
    if (bid < 4096) {
        int tid = bid * 256 + threadIdx.x;
        int e = tid << 3;
        int c = e & (Cdim - 1);
        int t = (e >> 10) & (Tdim - 1);
        float xf[8], xxf[8], mk[8], mv[8], mr[8];
        *(float4*)(xf)     = *(const float4*)(x + e);
        *(float4*)(xf + 4) = *(const float4*)(x + e + 4);
        if (t != 0) {
            *(float4*)(xxf)     = *(const float4*)(x + e - Cdim);
            *(float4*)(xxf + 4) = *(const float4*)(x + e - Cdim + 4);
        } else {
#pragma unroll
            for (int j = 0; j < 8; j++) xxf[j] = 0.f;
        }
        *(float4*)(mk)     = *(const float4*)(tmk + c);
        *(float4*)(mk + 4) = *(const float4*)(tmk + c + 4);
        *(float4*)(mv)     = *(const float4*)(tmv + c);
        *(float4*)(mv + 4) = *(const float4*)(tmv + c + 4);
        *(float4*)(mr)     = *(const float4*)(tmr + c);
        *(float4*)(mr + 4) = *(const float4*)(tmr + c + 4);
        u16 ok[8], ov[8], orr[8];
#pragma unroll
        for (int j = 0; j < 8; j++) {
            float d = xf[j] - xxf[j];
            ok[j]  = f2bf(xxf[j] + d * mk[j]);
            ov[j]  = f2bf(xxf[j] + d * mv[j]);
            orr[j] = f2bf(xxf[j] + d * mr[j]);
        }
        *(uint4*)(xk + e) = *(const uint4*)ok;
        *(uint4*)(xv + e) = *(const uint4*)ov;
        *(uint4*)(xr + e) = *(const uint4*)orr;
    } else {
        int wb = bid - 4096;                 // 0..2047
        int m = wb >> 9;                     // matrix 0..3
        const float* src; u16* dst;
        switch (m) {
            case 0: src = w0; dst = o0; break;
            case 1: src = w1; dst = o1; break;
            case 2: src = w2; dst = o2; break;
            default: src = w3; dst = o3; break;
        }
        int i = (((wb & 511) << 8) + threadIdx.x) << 3;
        float a[8];
        *(float4*)(a)     = *(const float4*)(src + i);
        *(float4*)(a + 4) = *(const float4*)(src + i + 4);
        u16 o[8];
#pragma unroll
        for (int j = 0; j < 8; j++) o[j] = f2bf(a[j]);
        *(uint4*)(dst + i) = *(const uint4*)o;
    }
}

// ---- GEMM body: C[8192,1024] = A[8192,1024] * Bw[1024,1024]^T (bf16 MFMA) -----
// 256x128 tile, BK=64, 512 threads = 8 waves (4M x 2N), wave tile 64x64.
// 3-deep K-tile LDS ring (A 3x32KB + B 3x16KB = 144 KiB): while computing
// tile t we issue tile t+2's 6 global_load_lds per wave. Steady-state
// checkpoint per tile: s_waitcnt vmcnt(6) + raw s_barrier — loads stay in
// flight across barriers (T4); no drain-to-0 until the epilogue.
// LDS layout: element (row,k) at byte (row*128 + 2k) ^ ((row&7)<<4)  [T2
// XOR swizzle]. global_load_lds writes linearly, so the SOURCE address is
// inverse-swizzled (chunk = (tid&7) ^ ((tid>>3)&7)) and reads apply the
// same XOR — 16 fr-lanes of a ds_read_b128 then cover all 32 banks 2-way.
template <int BF16OUT>
__device__ __forceinline__ void gemm_body256(
    const u16* __restrict__ A, const u16* __restrict__ Bw, void* __restrict__ Cout,
    u16* As, u16* Bs, int bm, int bn)
{
    const int K = Cdim, N = Cdim;
    const int NT = K / 64;                    // 16 K-tiles
    const int tid = threadIdx.x;
    const int lane = tid & 63, wave = tid >> 6;
    const int wm = (wave >> 1) << 6;          // 0,64,128,192
    const int wn = (wave & 1) << 6;           // 0,64
    const int fr = lane & 15, quad = lane >> 4;
    const int lwo = wave << 9;                // wave*512 u16 (1KB per wave-issue)

    // staging source (inverse-swizzled global address, linear LDS dest)
    const int srow = tid >> 3;                           // 0..63
    const int schunk = ((tid & 7) ^ (srow & 7)) << 3;    // u16 offset in row
    const u16* gaS = A  + (size_t)(bm * 256 + srow) * K + schunk;
    const u16* gbS = Bw + (size_t)(bn * 128 + srow) * K + schunk;
    const size_t rstep = (size_t)64 * K;

    // swizzled read k-offsets (u16 units) for kstep 0 / 1
    const int koff0 = ((quad << 3))      ^ ((fr & 7) << 3);
    const int koff1 = (32 + (quad << 3)) ^ ((fr & 7) << 3);

    f32x4 acc[4][4];
#pragma unroll
    for (int i = 0; i < 4; i++)
#pragma unroll
        for (int j = 0; j < 4; j++)
            acc[i][j] = (f32x4){0.f, 0.f, 0.f, 0.f};

    // issue one K-tile's staging: 4 A-chunks + 2 B-chunks per wave
    auto issue2 = [&](int T, int aoff, int boff) {
        const u16* ga = gaS + T * 64;
        u16* la = As + aoff + lwo;
        gload16(ga,             la);
        gload16(ga + rstep,     la + 4096);
        gload16(ga + 2 * rstep, la + 8192);
        gload16(ga + 3 * rstep, la + 12288);
        const u16* gb = gbS + T * 64;
        u16* lb = Bs + boff + lwo;
        gload16(gb,         lb);
        gload16(gb + rstep, lb + 4096);
    };

    // one K-tile of compute: 4 quadrant-phases, 8 MFMA each (32 total/wave)
    auto compute_tile = [&](int ac, int bc) {
        const u16* __restrict__ Ab = As + ac;
        const u16* __restrict__ Bb = Bs + bc;
        __builtin_amdgcn_s_setprio(1);
#pragma unroll
        for (int ph = 0; ph < 4; ++ph) {
            const int qi = ph >> 1, qj = ph & 1;
            bf16x8 af[2][2], bfr[2][2];
#pragma unroll
            for (int d = 0; d < 2; ++d) {
                const int ra = (wm + (qi * 2 + d) * 16 + fr) << 6;
                af[d][0] = *(const bf16x8*)(Ab + ra + koff0);
                af[d][1] = *(const bf16x8*)(Ab + ra + koff1);
                const int rb = (wn + (qj * 2 + d) * 16 + fr) << 6;
                bfr[d][0] = *(const bf16x8*)(Bb + rb + koff0);
                bfr[d][1] = *(const bf16x8*)(Bb + rb + koff1);
            }
#pragma unroll
            for (int di = 0; di < 2; ++di)
#pragma unroll
                for (int dj = 0; dj < 2; ++dj) {
                    acc[qi * 2 + di][qj * 2 + dj] =
                        __builtin_amdgcn_mfma_f32_16x16x32_bf16(
                            af[di][0], bfr[dj][0], acc[qi * 2 + di][qj * 2 + dj], 0, 0, 0);
                    acc[qi * 2 + di][qj * 2 + dj] =
                        __builtin_amdgcn_mfma_f32_16x16x32_bf16(
                            af[di][1], bfr[dj][1], acc[qi * 2 + di][qj * 2 + dj], 0, 0, 0);
                }
        }
        __builtin_amdgcn_s_setprio(0);
    };

    // prologue: stage tiles 0 and 1; wait until tile 0 landed (6 still in flight)
    issue2(0, 0, 0);
    issue2(1, 16384, 8192);
    asm volatile("s_waitcnt vmcnt(6)" ::: "memory");
    __builtin_amdgcn_s_barrier();
    __builtin_amdgcn_sched_barrier(0);

    int a_c = 0, b_c = 0;                 // compute ring offsets (u16)
    int a_s = 32768, b_s = 16384;         // stage ring offsets (tile t+2)
#pragma unroll 1
    for (int t = 0; t <= NT - 3; ++t) {
        issue2(t + 2, a_s, b_s);
        compute_tile(a_c, b_c);
        // all tiles <= t+1 landed; only tile t+2's 6 loads may remain in flight
        asm volatile("s_waitcnt vmcnt(6)" ::: "memory");
        __builtin_amdgcn_s_barrier();
        __builtin_amdgcn_sched_barrier(0);
        a_c += 16384; if (a_c == 49152) a_c = 0;
        b_c += 8192;  if (b_c == 24576) b_c = 0;
        a_s += 16384; if (a_s == 49152) a_s = 0;
        b_s += 8192;  if (b_s == 24576) b_s = 0;
    }
    compute_tile(a_c, b_c);               // tile NT-2
    asm volatile("s_waitcnt vmcnt(0)" ::: "memory");
    __builtin_amdgcn_s_barrier();
    __builtin_amdgcn_sched_barrier(0);
    a_c += 16384; if (a_c == 49152) a_c = 0;
    b_c += 8192;  if (b_c == 24576) b_c = 0;
    compute_tile(a_c, b_c);               // tile NT-1

    // C/D layout: row = quad*4 + reg, col = lane&15  [m89-verified]
    const int gr0 = bm * 256 + wm + quad * 4;
    const int gc0 = bn * 128 + wn + fr;
#pragma unroll
    for (int i = 0; i < 4; i++)
#pragma unroll
        for (int j = 0; j < 4; j++)
#pragma unroll
            for (int r = 0; r < 4; r++) {
                int gr = gr0 + i * 16 + r;
                int gc = gc0 + j * 16;
                float val = acc[i][j][r];
                if (BF16OUT)
                    ((u16*)Cout)[(size_t)gr * N + gc] = f2bf(val);
                else
                    ((float*)Cout)[(size_t)gr * N + gc] = val;
            }
}

// grouped GEMM for k/v/r (blockIdx.z selects operand set), bf16 out
// XCD swizzle: bm = bx&31 -> blocks sharing an A row-panel satisfy
// bx%8 = bm%8, so they co-reside on one XCD (L2-local A reuse).
__global__ __launch_bounds__(512) void gemm3_kernel(
    const u16* __restrict__ xk, const u16* __restrict__ xv, const u16* __restrict__ xr,
    const u16* __restrict__ wk, const u16* __restrict__ wv, const u16* __restrict__ wr,
    u16* __restrict__ ck, u16* __restrict__ cv, u16* __restrict__ cr)
{
    __shared__ __align__(16) u16 As[3 * 16384];   // 96 KiB
    __shared__ __align__(16) u16 Bs[3 * 8192];    // 48 KiB
    const u16* A; const u16* Bw; u16* Cout;
    switch (blockIdx.z) {
        case 0:  A = xk; Bw = wk; Cout = ck; break;
        case 1:  A = xv; Bw = wv; Cout = cv; break;
        default: A = xr; Bw = wr; Cout = cr; break;
    }
    int bx = blockIdx.x;
    gemm_body256<1>(A, Bw, (void*)Cout, As, Bs, bx & 31, bx >> 5);
}

// final GEMM, f32 out
__global__ __launch_bounds__(512) void gemmo_kernel(
    const u16* __restrict__ A, const u16* __restrict__ Bw, float* __restrict__ Cout)
{
    __shared__ __align__(16) u16 As[3 * 16384];
    __shared__ __align__(16) u16 Bs[3 * 8192];
    int bx = blockIdx.x;
    gemm_body256<0>(A, Bw, (void*)Cout, As, Bs, bx & 31, bx >> 5);
}

// ---- WKV scan + sigmoid(r) gate; register double-buffered prefetch ------------
#define WTC 16

#define LOADCHUNK(KA, VA, RA, T0)                                        \
    _Pragma("unroll")                                                    \
    for (int s = 0; s < WTC; s++) {                                      \
        size_t idx = base + (size_t)((T0) + s) * Cdim;                   \
        KA[s] = kb[idx]; VA[s] = vb[idx]; RA[s] = rb[idx];               \
    }

#define COMPCHUNK(KA, VA, RA, T0)                                        \
    _Pragma("unroll")                                                    \
    for (int s = 0; s < WTC; s++) {                                      \
        float kt = bf2f(KA[s]);                                          \
        float vt = bf2f(VA[s]);                                          \
        float rt = bf2f(RA[s]);                                          \
        float uk = u + kt;                                               \
        float no = fmaxf(o, uk);                                         \
        float Ae = __expf(o - no);                                       \
        float Bc = __expf(uk - no);                                      \
        float num = Ae * p + Bc * vt;                                    \
        float den = Ae * q + Bc;                                         \
        float y = num * __builtin_amdgcn_rcpf(den);                      \
        float sr = __builtin_amdgcn_rcpf(1.f + __expf(-rt));             \
        rwkv[base + (size_t)((T0) + s) * Cdim] = f2bf(y * sr);           \
        float wo = w + o;                                                \
        float no2 = fmaxf(wo, kt);                                       \
        float A2 = __expf(wo - no2);                                     \
        float B2 = __expf(kt - no2);                                     \
        p = A2 * p + B2 * vt;                                            \
        q = A2 * q + B2;                                                 \
        o = no2;                                                         \
    }

__global__ __launch_bounds__(64) void wkv_kernel(
    const u16* __restrict__ kb, const u16* __restrict__ vb,
    const u16* __restrict__ rb, const float* __restrict__ td,
    const float* __restrict__ tfirst, u16* __restrict__ rwkv)
{
    int lane = threadIdx.x;
    int blk = blockIdx.x;            // 512 blocks
    int b = blk >> 4;
    int c = ((blk & 15) << 6) + lane;
    float w = -__expf(td[c]);
    float u = tfirst[c];
    const size_t base = (size_t)b * Tdim * Cdim + c;

    u32 kA[WTC], vA[WTC], rA[WTC];
    u32 kB[WTC], vB[WTC], rB[WTC];
    float p = 0.f, q = 0.f, o = -1e38f;

    LOADCHUNK(kA, vA, rA, 0)
    for (int t0 = 0; t0 < Tdim; t0 += 2 * WTC) {
        LOADCHUNK(kB, vB, rB, t0 + WTC)
        COMPCHUNK(kA, vA, rA, t0)
        if (t0 + 2 * WTC < Tdim) {
            LOADCHUNK(kA, vA, rA, t0 + 2 * WTC)
        }
        COMPCHUNK(kB, vB, rB, t0 + WTC)
    }
}

extern "C" void kernel_launch(void* const* d_in, const int* in_sizes, int n_in,
                              void* d_out, int out_size, void* d_ws, size_t ws_size,
                              hipStream_t stream) {
    (void)in_sizes; (void)n_in; (void)out_size; (void)ws_size;
    const float* x   = (const float*)d_in[0];
    const float* td  = (const float*)d_in[1];
    const float* tfi = (const float*)d_in[2];
    const float* tmk = (const float*)d_in[3];
    const float* tmv = (const float*)d_in[4];
    const float* tmr = (const float*)d_in[5];
    const float* Wk  = (const float*)d_in[6];
    const float* Wv  = (const float*)d_in[7];
    const float* Wr  = (const float*)d_in[8];
    const float* Wo  = (const float*)d_in[9];

    char* ws = (char*)d_ws;
    const size_t MiB = (size_t)1 << 20;
    u16* xk    = (u16*)(ws);             // [0,16)
    u16* xv    = (u16*)(ws + 16 * MiB);  // [16,32)
    u16* xr    = (u16*)(ws + 32 * MiB);  // [32,48)
    u16* wkb   = (u16*)(ws + 48 * MiB);  // [48,50)
    u16* wvb   = (u16*)(ws + 50 * MiB);  // [50,52)
    u16* wrb   = (u16*)(ws + 52 * MiB);  // [52,54)
    u16* wob   = (u16*)(ws + 54 * MiB);  // [54,56)
    u16* kb    = (u16*)(ws + 56 * MiB);  // [56,72)
    u16* vb    = (u16*)(ws + 72 * MiB);  // [72,88)
    u16* rb    = (u16*)(ws + 88 * MiB);  // [88,104) — no alias: gemm3 z's run concurrently
    u16* rwkvb = (u16*)(ws);             // [0,16) — overlaps xk (dead after gemm3)

    prep_fused<<<6144, 256, 0, stream>>>(x, tmk, tmv, tmr, xk, xv, xr,
                                         Wk, Wv, Wr, Wo, wkb, wvb, wrb, wob);

    gemm3_kernel<<<dim3(256, 1, 3), 512, 0, stream>>>(xk, xv, xr, wkb, wvb, wrb,
                                                      kb, vb, rb);

    wkv_kernel<<<512, 64, 0, stream>>>(kb, vb, rb, td, tfi, rwkvb);

    gemmo_kernel<<<256, 512, 0, stream>>>(rwkvb, wob, (float*)d_out);
}

// Round 2
// 229.299 us; speedup vs baseline: 1.0630x; 1.0630x over previous
//
#include <hip/hip_runtime.h>

#define Bdim 32
#define Tdim 256
#define Cdim 1024

typedef unsigned short u16;
typedef unsigned int u32;
typedef __bf16 bf16x8 __attribute__((ext_vector_type(8)));
typedef float f32x4 __attribute__((ext_vector_type(4)));

__device__ __forceinline__ float bf2f(u32 u) {
    union { u32 i; float f; } v; v.i = u << 16; return v.f;
}
__device__ __forceinline__ u16 f2bf(float f) {
    union { float f; u32 i; } v; v.f = f;
    u32 u = v.i;
    return (u16)((u + 0x7fffu + ((u >> 16) & 1u)) >> 16);  // RNE
}

__device__ __forceinline__ void gload16(const u16* g, u16* l) {
    __builtin_amdgcn_global_load_lds(
        (__attribute__((address_space(1))) const void*)g,
        (__attribute__((address_space(3))) void*)l, 16, 0, 0);
}

// ---- fused prep (x mixing -> bf16) + weight convert ---------------------------
__global__ __launch_bounds__(256) void prep_fused(
    const float* __restrict__ x, const float* __restrict__ tmk,
    const float* __restrict__ tmv, const float* __restrict__ tmr,
    u16* __restrict__ xk, u16* __restrict__ xv, u16* __restrict__ xr,
    const float* __restrict__ w0, const float* __restrict__ w1,
    const float* __restrict__ w2, const float* __restrict__ w3,
    u16* __restrict__ o0, u16* __restrict__ o1,
    u16* __restrict__ o2, u16* __restrict__ o3)
{
    int bid = blockIdx.x;
    if (bid < 4096) {
        int tid = bid * 256 + threadIdx.x;
        int e = tid << 3;
        int c = e & (Cdim - 1);
        int t = (e >> 10) & (Tdim - 1);
        float xf[8], xxf[8], mk[8], mv[8], mr[8];
        *(float4*)(xf)     = *(const float4*)(x + e);
        *(float4*)(xf + 4) = *(const float4*)(x + e + 4);
        if (t != 0) {
            *(float4*)(xxf)     = *(const float4*)(x + e - Cdim);
            *(float4*)(xxf + 4) = *(const float4*)(x + e - Cdim + 4);
        } else {
#pragma unroll
            for (int j = 0; j < 8; j++) xxf[j] = 0.f;
        }
        *(float4*)(mk)     = *(const float4*)(tmk + c);
        *(float4*)(mk + 4) = *(const float4*)(tmk + c + 4);
        *(float4*)(mv)     = *(const float4*)(tmv + c);
        *(float4*)(mv + 4) = *(const float4*)(tmv + c + 4);
        *(float4*)(mr)     = *(const float4*)(tmr + c);
        *(float4*)(mr + 4) = *(const float4*)(tmr + c + 4);
        u16 ok[8], ov[8], orr[8];
#pragma unroll
        for (int j = 0; j < 8; j++) {
            float d = xf[j] - xxf[j];
            ok[j]  = f2bf(xxf[j] + d * mk[j]);
            ov[j]  = f2bf(xxf[j] + d * mv[j]);
            orr[j] = f2bf(xxf[j] + d * mr[j]);
        }
        *(uint4*)(xk + e) = *(const uint4*)ok;
        *(uint4*)(xv + e) = *(const uint4*)ov;
        *(uint4*)(xr + e) = *(const uint4*)orr;
    } else {
        int wb = bid - 4096;                 // 0..2047
        int m = wb >> 9;                     // matrix 0..3
        const float* src; u16* dst;
        switch (m) {
            case 0: src = w0; dst = o0; break;
            case 1: src = w1; dst = o1; break;
            case 2: src = w2; dst = o2; break;
            default: src = w3; dst = o3; break;
        }
        int i = (((wb & 511) << 8) + threadIdx.x) << 3;
        float a[8];
        *(float4*)(a)     = *(const float4*)(src + i);
        *(float4*)(a + 4) = *(const float4*)(src + i + 4);
        u16 o[8];
#pragma unroll
        for (int j = 0; j < 8; j++) o[j] = f2bf(a[j]);
        *(uint4*)(dst + i) = *(const uint4*)o;
    }
}

// ---- GEMM body: C[8192,1024] = A[8192,1024] * Bw[1024,1024]^T (bf16 MFMA) -----
// 256x128 tile, BK=64, 512 threads = 8 waves (4M x 2N), wave tile 64x64.
// m201-style fine-phase schedule: each K-tile = 2 phases (one per 32-wide
// kstep). Phase = { 8 ds_read_b128 (4 A-frags + 4 B-frags, each read ONCE)
// || issue 3 global_load_lds for tile t+2 -> s_barrier -> lgkmcnt(0) ->
// setprio(1) -> 16 independent MFMAs -> setprio(0) -> s_barrier }.
// Counted vmcnt (T4): once per K-tile, vmcnt(6) = tile t+2's loads still in
// flight (tile t+1 guaranteed landed); vmcnt(0) only at tile NT-2.
// LDS: 3-deep K-tile rings (A 3x32KB, B 3x16KB = 144 KiB). Tile t+2's slot
// (t+2)%3 is disjoint from the slots read during tile t -> no LDS hazard.
// T2 XOR swizzle: element (row,k) at byte (row*128 + 2k) ^ ((row&7)<<4);
// gload_lds writes linearly so the global SOURCE is inverse-swizzled
// (chunk = (tid&7) ^ ((tid>>3)&7)); reads apply the same XOR. Within each
// 16-lane group a ds_read_b128 hits 8 chunk-cols x 2 lanes = 2-way = free.
// (Round-1 measured SQ_LDS_BANK_CONFLICT = 0 with this exact swizzle.)
template <int BF16OUT>
__device__ __forceinline__ void gemm_body256(
    const u16* __restrict__ A, const u16* __restrict__ Bw, void* __restrict__ Cout,
    u16* As, u16* Bs, int bm, int bn)
{
    const int K = Cdim, N = Cdim;
    const int NT = K / 64;                    // 16 K-tiles
    const int tid = threadIdx.x;
    const int lane = tid & 63, wave = tid >> 6;
    const int wm = (wave >> 1) << 6;          // 0,64,128,192
    const int wn = (wave & 1) << 6;           // 0,64
    const int fr = lane & 15, quad = lane >> 4;
    const int lwo = wave << 9;                // wave*512 u16 (1KB per wave-issue)

    // staging source (inverse-swizzled global address, linear LDS dest)
    const int srow = tid >> 3;                           // 0..63
    const int schunk = ((tid & 7) ^ (srow & 7)) << 3;    // u16 offset in row
    const u16* gaS = A  + (size_t)(bm * 256 + srow) * K + schunk;
    const u16* gbS = Bw + (size_t)(bn * 128 + srow) * K + schunk;
    const size_t rstep = (size_t)64 * K;

    // swizzled read k-offsets (u16 units) for kstep 0 / 1; frag rows are
    // 16-aligned + fr, so row&7 == fr&7.
    const int koff0 = (((0 + quad) ^ (fr & 7)) << 3);
    const int koff1 = (((4 + quad) ^ (fr & 7)) << 3);
    const int arow = wm + fr;
    const int brow = wn + fr;

    f32x4 acc[4][4];
#pragma unroll
    for (int i = 0; i < 4; i++)
#pragma unroll
        for (int j = 0; j < 4; j++)
            acc[i][j] = (f32x4){0.f, 0.f, 0.f, 0.f};

    // staging: A K-tile = 4 loads/thread (row-groups 0..3), B = 2 loads/thread
    auto issueA3 = [&](int T, int aoff) {          // A row-groups 0..2
        const u16* ga = gaS + T * 64;
        u16* la = As + aoff + lwo;
        gload16(ga,             la);
        gload16(ga + rstep,     la + 4096);
        gload16(ga + 2 * rstep, la + 8192);
    };
    auto issueA1B2 = [&](int T, int aoff, int boff) {  // A row-group 3 + B both
        const u16* ga = gaS + T * 64;
        gload16(ga + 3 * rstep, As + aoff + lwo + 12288);
        const u16* gb = gbS + T * 64;
        u16* lb = Bs + boff + lwo;
        gload16(gb,         lb);
        gload16(gb + rstep, lb + 4096);
    };

#define MFMA16(AR, BR)                                                   \
    _Pragma("unroll")                                                    \
    for (int i = 0; i < 4; ++i)                                          \
        _Pragma("unroll")                                                \
        for (int j = 0; j < 4; ++j)                                      \
            acc[i][j] = __builtin_amdgcn_mfma_f32_16x16x32_bf16(         \
                AR[i], BR[j], acc[i][j], 0, 0, 0);

    // prologue: stage tiles 0 and 1 fully; wait until tile 0 landed
    issueA3(0, 0);
    issueA1B2(0, 0, 0);
    issueA3(1, 16384);
    issueA1B2(1, 16384, 8192);
    asm volatile("s_waitcnt vmcnt(6)" ::: "memory");
    __builtin_amdgcn_s_barrier();

    int a_c = 0, b_c = 0;                 // compute ring offsets (u16)
    int a_s = 32768, b_s = 16384;         // stage ring offsets (tile t+2)
#pragma unroll 1
    for (int t = 0; t < NT; ++t) {
        const u16* __restrict__ Ab = As + a_c;
        const u16* __restrict__ Bb = Bs + b_c;
        const bool st = (t + 2 < NT);
        bf16x8 a[4], b[4];

        // ---- phase 1 (kstep 0) ----
#pragma unroll
        for (int i = 0; i < 4; ++i)
            a[i] = *(const bf16x8*)(Ab + (arow + i * 16) * 64 + koff0);
#pragma unroll
        for (int j = 0; j < 4; ++j)
            b[j] = *(const bf16x8*)(Bb + (brow + j * 16) * 64 + koff0);
        if (st) issueA3(t + 2, a_s);
        __builtin_amdgcn_s_barrier();
        asm volatile("s_waitcnt lgkmcnt(0)" ::: "memory");
        __builtin_amdgcn_s_setprio(1);
        MFMA16(a, b)
        __builtin_amdgcn_s_setprio(0);
        __builtin_amdgcn_s_barrier();

        // ---- phase 2 (kstep 1) ----
#pragma unroll
        for (int i = 0; i < 4; ++i)
            a[i] = *(const bf16x8*)(Ab + (arow + i * 16) * 64 + koff1);
#pragma unroll
        for (int j = 0; j < 4; ++j)
            b[j] = *(const bf16x8*)(Bb + (brow + j * 16) * 64 + koff1);
        if (st) issueA1B2(t + 2, a_s, b_s);
        __builtin_amdgcn_s_barrier();
        asm volatile("s_waitcnt lgkmcnt(0)" ::: "memory");
        __builtin_amdgcn_s_setprio(1);
        MFMA16(a, b)
        __builtin_amdgcn_s_setprio(0);
        // counted checkpoint: tile t+1 (issued during t-1) must be landed;
        // only tile t+2's 6 loads (issued this tile) may stay in flight.
        if (st) {
            asm volatile("s_waitcnt vmcnt(6)" ::: "memory");
        } else if (t == NT - 2) {
            asm volatile("s_waitcnt vmcnt(0)" ::: "memory");
        }
        __builtin_amdgcn_s_barrier();

        a_c += 16384; if (a_c == 49152) a_c = 0;
        b_c += 8192;  if (b_c == 24576) b_c = 0;
        a_s += 16384; if (a_s == 49152) a_s = 0;
        b_s += 8192;  if (b_s == 24576) b_s = 0;
    }
#undef MFMA16

    // C/D layout: row = quad*4 + reg, col = lane&15  [m89-verified]
    const int gr0 = bm * 256 + wm + quad * 4;
    const int gc0 = bn * 128 + wn + fr;
#pragma unroll
    for (int i = 0; i < 4; i++)
#pragma unroll
        for (int j = 0; j < 4; j++)
#pragma unroll
            for (int r = 0; r < 4; r++) {
                int gr = gr0 + i * 16 + r;
                int gc = gc0 + j * 16;
                float val = acc[i][j][r];
                if (BF16OUT)
                    ((u16*)Cout)[(size_t)gr * N + gc] = f2bf(val);
                else
                    ((float*)Cout)[(size_t)gr * N + gc] = val;
            }
}

// grouped GEMM for k/v/r (blockIdx.z selects operand set), bf16 out
// XCD swizzle: bm = bx&31 -> blocks sharing an A row-panel satisfy
// bx%8 = bm%8, so they co-reside on one XCD (L2-local A reuse).
__global__ __launch_bounds__(512) void gemm3_kernel(
    const u16* __restrict__ xk, const u16* __restrict__ xv, const u16* __restrict__ xr,
    const u16* __restrict__ wk, const u16* __restrict__ wv, const u16* __restrict__ wr,
    u16* __restrict__ ck, u16* __restrict__ cv, u16* __restrict__ cr)
{
    __shared__ __align__(16) u16 As[3 * 16384];   // 96 KiB
    __shared__ __align__(16) u16 Bs[3 * 8192];    // 48 KiB
    const u16* A; const u16* Bw; u16* Cout;
    switch (blockIdx.z) {
        case 0:  A = xk; Bw = wk; Cout = ck; break;
        case 1:  A = xv; Bw = wv; Cout = cv; break;
        default: A = xr; Bw = wr; Cout = cr; break;
    }
    int bx = blockIdx.x;
    gemm_body256<1>(A, Bw, (void*)Cout, As, Bs, bx & 31, bx >> 5);
}

// final GEMM, f32 out
__global__ __launch_bounds__(512) void gemmo_kernel(
    const u16* __restrict__ A, const u16* __restrict__ Bw, float* __restrict__ Cout)
{
    __shared__ __align__(16) u16 As[3 * 16384];
    __shared__ __align__(16) u16 Bs[3 * 8192];
    int bx = blockIdx.x;
    gemm_body256<0>(A, Bw, (void*)Cout, As, Bs, bx & 31, bx >> 5);
}

// ---- WKV scan + sigmoid(r) gate; register double-buffered prefetch ------------
#define WTC 16

#define LOADCHUNK(KA, VA, RA, T0)                                        \
    _Pragma("unroll")                                                    \
    for (int s = 0; s < WTC; s++) {                                      \
        size_t idx = base + (size_t)((T0) + s) * Cdim;                   \
        KA[s] = kb[idx]; VA[s] = vb[idx]; RA[s] = rb[idx];               \
    }

#define COMPCHUNK(KA, VA, RA, T0)                                        \
    _Pragma("unroll")                                                    \
    for (int s = 0; s < WTC; s++) {                                      \
        float kt = bf2f(KA[s]);                                          \
        float vt = bf2f(VA[s]);                                          \
        float rt = bf2f(RA[s]);                                          \
        float uk = u + kt;                                               \
        float no = fmaxf(o, uk);                                         \
        float Ae = __expf(o - no);                                       \
        float Bc = __expf(uk - no);                                      \
        float num = Ae * p + Bc * vt;                                    \
        float den = Ae * q + Bc;                                         \
        float y = num * __builtin_amdgcn_rcpf(den);                      \
        float sr = __builtin_amdgcn_rcpf(1.f + __expf(-rt));             \
        rwkv[base + (size_t)((T0) + s) * Cdim] = f2bf(y * sr);           \
        float wo = w + o;                                                \
        float no2 = fmaxf(wo, kt);                                       \
        float A2 = __expf(wo - no2);                                     \
        float B2 = __expf(kt - no2);                                     \
        p = A2 * p + B2 * vt;                                            \
        q = A2 * q + B2;                                                 \
        o = no2;                                                         \
    }

__global__ __launch_bounds__(64) void wkv_kernel(
    const u16* __restrict__ kb, const u16* __restrict__ vb,
    const u16* __restrict__ rb, const float* __restrict__ td,
    const float* __restrict__ tfirst, u16* __restrict__ rwkv)
{
    int lane = threadIdx.x;
    int blk = blockIdx.x;            // 512 blocks
    int b = blk >> 4;
    int c = ((blk & 15) << 6) + lane;
    float w = -__expf(td[c]);
    float u = tfirst[c];
    const size_t base = (size_t)b * Tdim * Cdim + c;

    u32 kA[WTC], vA[WTC], rA[WTC];
    u32 kB[WTC], vB[WTC], rB[WTC];
    float p = 0.f, q = 0.f, o = -1e38f;

    LOADCHUNK(kA, vA, rA, 0)
    for (int t0 = 0; t0 < Tdim; t0 += 2 * WTC) {
        LOADCHUNK(kB, vB, rB, t0 + WTC)
        COMPCHUNK(kA, vA, rA, t0)
        if (t0 + 2 * WTC < Tdim) {
            LOADCHUNK(kA, vA, rA, t0 + 2 * WTC)
        }
        COMPCHUNK(kB, vB, rB, t0 + WTC)
    }
}

extern "C" void kernel_launch(void* const* d_in, const int* in_sizes, int n_in,
                              void* d_out, int out_size, void* d_ws, size_t ws_size,
                              hipStream_t stream) {
    (void)in_sizes; (void)n_in; (void)out_size; (void)ws_size;
    const float* x   = (const float*)d_in[0];
    const float* td  = (const float*)d_in[1];
    const float* tfi = (const float*)d_in[2];
    const float* tmk = (const float*)d_in[3];
    const float* tmv = (const float*)d_in[4];
    const float* tmr = (const float*)d_in[5];
    const float* Wk  = (const float*)d_in[6];
    const float* Wv  = (const float*)d_in[7];
    const float* Wr  = (const float*)d_in[8];
    const float* Wo  = (const float*)d_in[9];

    char* ws = (char*)d_ws;
    const size_t MiB = (size_t)1 << 20;
    u16* xk    = (u16*)(ws);             // [0,16)
    u16* xv    = (u16*)(ws + 16 * MiB);  // [16,32)
    u16* xr    = (u16*)(ws + 32 * MiB);  // [32,48)
    u16* wkb   = (u16*)(ws + 48 * MiB);  // [48,50)
    u16* wvb   = (u16*)(ws + 50 * MiB);  // [50,52)
    u16* wrb   = (u16*)(ws + 52 * MiB);  // [52,54)
    u16* wob   = (u16*)(ws + 54 * MiB);  // [54,56)
    u16* kb    = (u16*)(ws + 56 * MiB);  // [56,72)
    u16* vb    = (u16*)(ws + 72 * MiB);  // [72,88)
    u16* rb    = (u16*)(ws + 88 * MiB);  // [88,104) — no alias: gemm3 z's run concurrently
    u16* rwkvb = (u16*)(ws);             // [0,16) — overlaps xk (dead after gemm3)

    prep_fused<<<6144, 256, 0, stream>>>(x, tmk, tmv, tmr, xk, xv, xr,
                                         Wk, Wv, Wr, Wo, wkb, wvb, wrb, wob);

    gemm3_kernel<<<dim3(256, 1, 3), 512, 0, stream>>>(xk, xv, xr, wkb, wvb, wrb,
                                                      kb, vb, rb);

    wkv_kernel<<<512, 64, 0, stream>>>(kb, vb, rb, td, tfi, rwkvb);

    gemmo_kernel<<<256, 512, 0, stream>>>(rwkvb, wob, (float*)d_out);
}